// Round 1
// baseline (3986.623 us; speedup 1.0000x reference)
//
#include <hip/hip_runtime.h>

// Voxelizer: B=2, C=32 -> BC=64 channel slabs, N=1e6 points, V=262144 voxels.
// ws layout: [ sums: BC*V floats | counts: V floats ]  = 68,157,440 bytes.

constexpr int BC = 64;          // B*C
constexpr int VOX = 262144;     // num_voxels (harness constant)

// Each thread owns 4 consecutive points (int4 idx load, float4 feat loads).
// bc loop is split across gridDim.y for occupancy (BC / gridDim.y slabs each).
__global__ __launch_bounds__(256) void voxel_scatter(
    const float* __restrict__ feat, const int* __restrict__ idx,
    float* __restrict__ sums, float* __restrict__ counts, int N)
{
    int t = blockIdx.x * blockDim.x + threadIdx.x;
    int n0 = t * 4;
    if (n0 >= N) return;
    int4 vi = *(const int4*)(idx + n0);

    // counts: only one y-slice contributes (avoid double counting)
    if (blockIdx.y == 0) {
        atomicAdd(&counts[vi.x], 1.0f);
        atomicAdd(&counts[vi.y], 1.0f);
        atomicAdd(&counts[vi.z], 1.0f);
        atomicAdd(&counts[vi.w], 1.0f);
    }

    int bc_per = BC / gridDim.y;
    int bc0 = blockIdx.y * bc_per;
    for (int bc = bc0; bc < bc0 + bc_per; ++bc) {
        float4 f = *(const float4*)(feat + (size_t)bc * N + n0);
        float* s = sums + (size_t)bc * VOX;
        atomicAdd(&s[vi.x], f.x);
        atomicAdd(&s[vi.y], f.y);
        atomicAdd(&s[vi.z], f.z);
        atomicAdd(&s[vi.w], f.w);
    }
}

__global__ __launch_bounds__(256) void voxel_gather(
    const float* __restrict__ sums, const float* __restrict__ counts,
    const int* __restrict__ idx, float* __restrict__ out, int N)
{
    int t = blockIdx.x * blockDim.x + threadIdx.x;
    int n0 = t * 4;
    if (n0 >= N) return;
    int4 vi = *(const int4*)(idx + n0);

    float4 inv;
    inv.x = 1.0f / fmaxf(counts[vi.x], 1.0f);
    inv.y = 1.0f / fmaxf(counts[vi.y], 1.0f);
    inv.z = 1.0f / fmaxf(counts[vi.z], 1.0f);
    inv.w = 1.0f / fmaxf(counts[vi.w], 1.0f);

    int bc_per = BC / gridDim.y;
    int bc0 = blockIdx.y * bc_per;
    for (int bc = bc0; bc < bc0 + bc_per; ++bc) {
        const float* s = sums + (size_t)bc * VOX;
        float4 o;
        o.x = s[vi.x] * inv.x;
        o.y = s[vi.y] * inv.y;
        o.z = s[vi.z] * inv.z;
        o.w = s[vi.w] * inv.w;
        *(float4*)(out + (size_t)bc * N + n0) = o;
    }
}

extern "C" void kernel_launch(void* const* d_in, const int* in_sizes, int n_in,
                              void* d_out, int out_size, void* d_ws, size_t ws_size,
                              hipStream_t stream) {
    const float* feat = (const float*)d_in[0];
    const int* idx = (const int*)d_in[1];
    float* out = (float*)d_out;
    int N = in_sizes[1];                 // 1,000,000

    float* sums = (float*)d_ws;
    float* counts = sums + (size_t)BC * VOX;
    size_t zero_bytes = ((size_t)BC * VOX + VOX) * sizeof(float);

    hipMemsetAsync(d_ws, 0, zero_bytes, stream);

    int threads = (N + 3) / 4;           // 250,000
    int blocks_x = (threads + 255) / 256;
    dim3 grid(blocks_x, 8, 1);           // 8 y-slices -> 8 bc slabs each

    voxel_scatter<<<grid, 256, 0, stream>>>(feat, idx, sums, counts, N);
    voxel_gather<<<grid, 256, 0, stream>>>(sums, counts, idx, out, N);
}